// Round 10
// baseline (56.815 us; speedup 1.0000x reference)
//
#include <hip/hip_runtime.h>
#include <hip/hip_bf16.h>

// EnhancedBCMLayer: block-circulant matmul == dense GEMM
//   out = X (4096x2048) @ W^T (2048x2048) + b, fp32 out
//   W[f*16+t][g*16+u] = iv[f, g, (t-u)&15]
// GEMM: BM=256 x BN=128 x BK=64, grid 256 (1 block/CU), 8 waves (4M x 2N),
// per-wave 64x64, 16x16x32 MFMA, 3 combined LDS buffers, 2-tile GLD prefetch.
// THIS ROUND: m201-faithful per-phase choreography (reads -> BAR -> lgkm(0)
// -> setprio+MFMA -> BAR), 2 phases/tile, vmcnt(6) once per tile at P1
// (FIFO-correct: covers A(t+1) AND B(t+1)). T1+T2+T5.

#define M_DIM 4096
#define N_DIM 2048
#define K_DIM 2048
#define BK 64
#define NT (K_DIM / BK)   // 32 K-tiles
#define BUFSZ 49152       // 48 KB: A [256 rows][128B] + B [128 rows][128B] at +32768

typedef __attribute__((ext_vector_type(8))) short bf16x8;
typedef __attribute__((ext_vector_type(4))) float f32x4;

typedef const __attribute__((address_space(1))) void gvoid_t;
typedef __attribute__((address_space(3))) void lvoid_t;

#define FENCE asm volatile("" ::: "memory")
#define BAR()  do { FENCE; __builtin_amdgcn_s_barrier(); FENCE; } while (0)
#define GLD(src, dst) __builtin_amdgcn_global_load_lds((gvoid_t*)(src), (lvoid_t*)(dst), 16, 0, 0)

// issue-order matters for vmcnt counting: A = 4 GLD, B = 2 GLD
#define STAGE_A(dst, src) (GLD((src) + 0 * 64 * K_DIM, (dst) + 0),     \
                           GLD((src) + 1 * 64 * K_DIM, (dst) + 8192),  \
                           GLD((src) + 2 * 64 * K_DIM, (dst) + 16384), \
                           GLD((src) + 3 * 64 * K_DIM, (dst) + 24576))
#define STAGE_B(dst, src) (GLD((src) + 0 * 64 * K_DIM, (dst) + 0),     \
                           GLD((src) + 1 * 64 * K_DIM, (dst) + 8192))

// fp32 -> bf16 RNE
__device__ __forceinline__ unsigned int f2bf(float f) {
  unsigned int u = __float_as_uint(f);
  return (u + 0x7fffu + ((u >> 16) & 1u)) >> 16;
}

// ---------------- fused prologue: cvt X -> bf16  |  expand iv -> dense bf16 W [N][K] ----------------
__global__ __launch_bounds__(256) void prep_kernel(const float* __restrict__ x,
                                                   const float* __restrict__ iv,
                                                   unsigned short* __restrict__ xb,
                                                   unsigned short* __restrict__ W) {
  int b = blockIdx.x;
  if (b < (M_DIM * K_DIM / 8) / 256) {
    int idx = b * 256 + threadIdx.x;          // one per 8 floats
    const float4* x4 = (const float4*)x;
    float4 a = x4[idx * 2 + 0];
    float4 c = x4[idx * 2 + 1];
    uint4 o;
    o.x = f2bf(a.x) | (f2bf(a.y) << 16);
    o.y = f2bf(a.z) | (f2bf(a.w) << 16);
    o.z = f2bf(c.x) | (f2bf(c.y) << 16);
    o.w = f2bf(c.z) | (f2bf(c.w) << 16);
    ((uint4*)xb)[idx] = o;
  } else {
    int idx = (b - (M_DIM * K_DIM / 8) / 256) * 256 + threadIdx.x;  // one per 8 weights
    int o  = idx >> 8;             // W row 0..2047
    int i0 = (idx & 255) * 8;      // col start
    int f = o >> 4, t = o & 15;
    int g = i0 >> 4, u0 = i0 & 15;
    const float* row = iv + (f * 128 + g) * 16;
    unsigned int p[4];
#pragma unroll
    for (int j = 0; j < 4; ++j) {
      unsigned int lo = f2bf(row[(t - (u0 + 2 * j + 0)) & 15]);
      unsigned int hi = f2bf(row[(t - (u0 + 2 * j + 1)) & 15]);
      p[j] = lo | (hi << 16);
    }
    ((uint4*)W)[idx] = make_uint4(p[0], p[1], p[2], p[3]);
  }
}

// ---------------- main GEMM ----------------
// LDS: 3 combined buffers of 48 KB: buf c at c*BUFSZ, A-part [256][128B],
// B-part at +32768 [128][128B]. Tile t lives in buf t%3.
// XOR-swizzle byte ^= (row&7)<<4 on both the GLD global source and the ds_read col.
__global__ __launch_bounds__(512, 2) void gemm_bias_kernel(const unsigned short* __restrict__ A,
                                                           const unsigned short* __restrict__ B,
                                                           const float* __restrict__ bias,
                                                           float* __restrict__ C) {
  __shared__ char lds[3 * BUFSZ];   // 144 KB

  const int tid = threadIdx.x;
  const int l   = tid & 63;
  const int w   = tid >> 6;       // wave 0..7
  const int wm  = w >> 1;         // wave row 0..3 (64 rows each)
  const int wn  = w & 1;          // wave col 0..1 (64 cols each)

  // T1: XCD-aware bijective swizzle (grid=256, 256%8==0)
  const int orig = blockIdx.x;
  const int swz  = (orig & 7) * 32 + (orig >> 3);
  const int bm   = swz >> 4;      // 0..15  (M tile)
  const int bn   = swz & 15;      // 0..15  (N tile)

  f32x4 acc[4][4] = {};

  // ---- staging addresses (inverse-swizzled global source, linear LDS dest) ----
  const int srow  = w * 8 + (l >> 3);               // 0..63
  const int sslot = (l & 7) ^ ((l >> 3) & 7);       // pre-swizzled K-slot
  const unsigned short* Asrc0 = A + (size_t)(bm * 256 + srow) * K_DIM + sslot * 8;
  const unsigned short* Bsrc0 = B + (size_t)(bn * 128 + srow) * K_DIM + sslot * 8;

  // ---- ds_read addresses (T2 swizzled) ----
  const int fr = l & 15;                            // fragment row within 16
  const int rxor = (l & 7) << 4;                    // (row&7)<<4
  const int aRow0 = (wm * 64 + fr) * 128;           // byte row base, + m*2048
  const int bRow0 = (wn * 64 + fr) * 128;           // + n*2048
  const int swzcol0 = (0 * 64 + (l >> 4) * 16) ^ rxor;  // K 0..31
  const int swzcol1 = (1 * 64 + (l >> 4) * 16) ^ rxor;  // K 32..63

  // single fragment set (m201 style: read -> barrier -> lgkm(0) -> MFMA)
  bf16x8 fa[4], fb[4];

#define LDA(BUF, SWZ)                                                   \
  do {                                                                  \
    const char* Ab_ = lds + (BUF) * BUFSZ;                              \
    const char* Bb_ = Ab_ + 32768;                                      \
    _Pragma("unroll")                                                   \
    for (int m = 0; m < 4; ++m)                                         \
      fa[m] = *(const bf16x8*)(Ab_ + aRow0 + m * 2048 + (SWZ));         \
    _Pragma("unroll")                                                   \
    for (int n = 0; n < 4; ++n)                                         \
      fb[n] = *(const bf16x8*)(Bb_ + bRow0 + n * 2048 + (SWZ));         \
  } while (0)

#define MFMA_CLUSTER()                                                  \
  do {                                                                  \
    asm volatile("s_waitcnt lgkmcnt(0)" ::: "memory");                  \
    __builtin_amdgcn_sched_barrier(0);                                  \
    __builtin_amdgcn_s_setprio(1);                                      \
    _Pragma("unroll")                                                   \
    for (int m = 0; m < 4; ++m)                                         \
      _Pragma("unroll")                                                 \
      for (int n = 0; n < 4; ++n)                                       \
        acc[m][n] = __builtin_amdgcn_mfma_f32_16x16x32_bf16(fa[m], fb[n], acc[m][n], 0, 0, 0); \
    __builtin_amdgcn_s_setprio(0);                                      \
    __builtin_amdgcn_sched_barrier(0);                                  \
  } while (0)

  // m201-style phase: {reads issue | GLD issue | [vmcnt] | BAR | lgkm(0) |
  //                    setprio+16 MFMA+setprio | BAR}
#define PHASE(BUF, SWZ, STAGE_STMT, VM_STMT)                            \
  do {                                                                  \
    LDA(BUF, SWZ);                                                      \
    STAGE_STMT;                                                         \
    VM_STMT;                                                            \
    BAR();                                                              \
    MFMA_CLUSTER();                                                     \
    BAR();                                                              \
  } while (0)

#define VM6 asm volatile("s_waitcnt vmcnt(6)" ::: "memory")
#define VM0 asm volatile("s_waitcnt vmcnt(0)" ::: "memory")
#define NOSTAGE (void)0
#define NOVM (void)0

  // Steady-state tile t (CUR=t%3, STG=(t+2)%3):
  // P0: LDA kc0 | STAGE_A(t+2) [queue -> A(t+1)4,B(t+1)2,A(t+2)4] | BAR | MFMA | BAR
  // P1: LDA kc1 | STAGE_B(t+2) [queue 12] | vmcnt(6): drains A(t+1)+B(t+1),
  //     leaves A(t+2)4+B(t+2)2 | BAR | MFMA | BAR
  // Buffer safety: STG's last readers were tile t-1 (same buf), done at t-1's
  // final barrier, which precedes these GLD issues in program order.
#define BODY(T, CUR, STG)                                               \
  do {                                                                  \
    PHASE(CUR, swzcol0, STAGE_A(lds + (STG) * BUFSZ + w * 1024, Asrc0 + ((T) + 2) * BK), NOVM); \
    PHASE(CUR, swzcol1, STAGE_B(lds + (STG) * BUFSZ + 32768 + w * 1024, Bsrc0 + ((T) + 2) * BK), VM6); \
  } while (0)

  // ---- prologue: stage A(0),B(0),A(1),B(1); drain tile 0 ----
  STAGE_A(lds + 0 * BUFSZ + w * 1024, Asrc0 + 0 * BK);
  STAGE_B(lds + 0 * BUFSZ + 32768 + w * 1024, Bsrc0 + 0 * BK);
  STAGE_A(lds + 1 * BUFSZ + w * 1024, Asrc0 + 1 * BK);
  STAGE_B(lds + 1 * BUFSZ + 32768 + w * 1024, Bsrc0 + 1 * BK);
  asm volatile("s_waitcnt vmcnt(6)" ::: "memory");  // A(0)+B(0) landed; tile-1 6 in flight
  BAR();

  // ---- main loop: tiles 0..29 (all stage t+2; unroll x3 for buf indices) ----
  for (int t = 0; t < NT - 2; t += 3) {
    BODY(t + 0, 0, 2);
    BODY(t + 1, 1, 0);
    BODY(t + 2, 2, 1);
  }

  // ---- tail: tile 30 (buf 0; no staging; vmcnt(0) at P1 drains A(31),B(31)) ----
  PHASE(0, swzcol0, NOSTAGE, NOVM);
  PHASE(0, swzcol1, NOSTAGE, VM0);
  // ---- tile 31 (buf 1; no barriers needed after reads) ----
  LDA(1, swzcol0);
  MFMA_CLUSTER();
  LDA(1, swzcol1);
  MFMA_CLUSTER();

  // ---- epilogue: C/D layout col=lane&15, row=(lane>>4)*4+reg ----
  const int row0 = bm * 256 + wm * 64 + (l >> 4) * 4;
  const int col0 = bn * 128 + wn * 64 + (l & 15);
#pragma unroll
  for (int n = 0; n < 4; ++n) {
    float bv = bias[col0 + n * 16];
#pragma unroll
    for (int m = 0; m < 4; ++m) {
#pragma unroll
      for (int j = 0; j < 4; ++j) {
        C[(size_t)(row0 + m * 16 + j) * N_DIM + (col0 + n * 16)] = acc[m][n][j] + bv;
      }
    }
  }
#undef BODY
#undef PHASE
#undef MFMA_CLUSTER
#undef LDA
#undef VM6
#undef VM0
#undef NOSTAGE
#undef NOVM
}

// ---------------- fallback (ws too small): direct fp32 ----------------
__global__ __launch_bounds__(256) void fallback_kernel(const float* __restrict__ x,
                                                       const float* __restrict__ iv,
                                                       const float* __restrict__ b,
                                                       float* __restrict__ out) {
  int idx = blockIdx.x * 256 + threadIdx.x;
  int Bn = idx >> 11, o = idx & 2047;
  int f = o >> 4, t = o & 15;
  const float* xr = x + (size_t)Bn * 2048;
  float acc = 0.f;
  for (int g = 0; g < 128; ++g) {
    const float* pr = iv + (f * 128 + g) * 16;
    const float* xg = xr + g * 16;
#pragma unroll
    for (int s = 0; s < 16; ++s) acc += pr[s] * xg[(t - s) & 15];
  }
  out[idx] = acc + b[o];
}

extern "C" void kernel_launch(void* const* d_in, const int* in_sizes, int n_in,
                              void* d_out, int out_size, void* d_ws, size_t ws_size,
                              hipStream_t stream) {
  const float* x    = (const float*)d_in[0];
  const float* iv   = (const float*)d_in[1];
  const float* bias = (const float*)d_in[2];
  float* out = (float*)d_out;

  const size_t xb_bytes = (size_t)M_DIM * K_DIM * 2;
  const size_t w_bytes  = (size_t)N_DIM * K_DIM * 2;
  if (ws_size < xb_bytes + w_bytes) {
    fallback_kernel<<<(M_DIM * N_DIM) / 256, 256, 0, stream>>>(x, iv, bias, out);
    return;
  }

  unsigned short* xb = (unsigned short*)d_ws;
  unsigned short* W  = xb + (size_t)M_DIM * K_DIM;

  const int cvt_blocks = (M_DIM * K_DIM / 8) / 256;   // 4096
  const int bw_blocks  = (N_DIM * K_DIM / 8) / 256;   // 2048
  prep_kernel<<<cvt_blocks + bw_blocks, 256, 0, stream>>>(x, iv, xb, W);

  gemm_bias_kernel<<<(M_DIM / 256) * (N_DIM / 128), 512, 0, stream>>>(xb, W, bias, out);
}